// Round 1
// baseline (208.006 us; speedup 1.0000x reference)
//
#include <hip/hip_runtime.h>

// Requires ws_size >= 56 MiB.
typedef short bf16x8 __attribute__((ext_vector_type(8)));
typedef float f32x4 __attribute__((ext_vector_type(4)));
typedef unsigned short ushort8 __attribute__((ext_vector_type(8)));
typedef unsigned short u16;

__device__ inline u16 f2bf(float f) {
  unsigned int u = __float_as_uint(f);
  u += 0x7fffu + ((u >> 16) & 1u);
  return (u16)(u >> 16);
}

__device__ inline void gload_lds16(const u16* g, u16* l) {
  __builtin_amdgcn_global_load_lds(
      (const __attribute__((address_space(1))) unsigned int*)g,
      (__attribute__((address_space(3))) unsigned int*)l, 16, 0, 0);
}

// ---------------- elementwise f32 -> bf16 ----------------
__global__ __launch_bounds__(256) void cvt_bf16(const float* __restrict__ in,
                                                u16* __restrict__ out, int n) {
  int i = (blockIdx.x * 256 + threadIdx.x) * 8;
  if (i >= n) return;
  float4 a = *(const float4*)(in + i);
  float4 b = *(const float4*)(in + i + 4);
  ushort8 o;
  o[0] = f2bf(a.x); o[1] = f2bf(a.y); o[2] = f2bf(a.z); o[3] = f2bf(a.w);
  o[4] = f2bf(b.x); o[5] = f2bf(b.y); o[6] = f2bf(b.z); o[7] = f2bf(b.w);
  *(ushort8*)(out + i) = o;
}

// ---------------- W[K][N] f32 -> Wt[N][K] bf16 ----------------
__global__ __launch_bounds__(256) void trans_w(const float* __restrict__ W,
                                               u16* __restrict__ Wt, int K, int N) {
  const int k0 = blockIdx.x * 64, n0 = blockIdx.y * 64;
  const int tx = threadIdx.x & 63, ty = threadIdx.x >> 6;
  __shared__ float t[64][65];
#pragma unroll
  for (int i = 0; i < 16; ++i) {
    int r = i * 4 + ty;
    t[r][tx] = W[(size_t)(k0 + r) * N + n0 + tx];
  }
  __syncthreads();
#pragma unroll
  for (int i = 0; i < 16; ++i) {
    int r = i * 4 + ty;
    Wt[(size_t)(n0 + r) * K + k0 + tx] = f2bf(t[tx][r]);
  }
}

// ---------------- V[bh][2048][64] -> Vt[bh][64][2048] (bf16) ----------------
__global__ __launch_bounds__(256) void v_trans(const u16* __restrict__ V,
                                               u16* __restrict__ Vt) {
  const int bh = blockIdx.y;
  const int n0 = blockIdx.x * 64;
  const int tid = threadIdx.x;
  __shared__ u16 t[64][68];
  const u16* src = V + ((size_t)bh * 2048 + n0) * 64;
  u16* dst = Vt + (size_t)bh * 64 * 2048;
#pragma unroll
  for (int i = 0; i < 2; ++i) {
    int r = i * 32 + (tid >> 3);
    int blk = tid & 7;
    ushort8 val = *(const ushort8*)&src[(size_t)r * 64 + blk * 8];
#pragma unroll
    for (int j = 0; j < 8; ++j) t[r][blk * 8 + j] = val[j];
  }
  __syncthreads();
#pragma unroll
  for (int i = 0; i < 2; ++i) {
    int d = i * 32 + (tid >> 3);
    int nb = tid & 7;
    ushort8 val;
#pragma unroll
    for (int j = 0; j < 8; ++j) val[j] = t[nb * 8 + j][d];
    *(ushort8*)&dst[(size_t)d * 2048 + n0 + nb * 8] = val;
  }
}

// ---------------- GEMM: C[M][N] = A[M][K] * Bt[N][K]^T  (m97 128^2 structure) ----
// MODE 0: epilogue + bias -> scatter Q(scaled)/K/V head-major bf16
// MODE 1: epilogue + bias -> f32 out
template <int MODE>
__global__ __launch_bounds__(256) void gemm_bt(
    const u16* __restrict__ A, const u16* __restrict__ Bt, int M, int N, int K,
    const float* __restrict__ bias, float* __restrict__ outF,
    u16* __restrict__ Qb, u16* __restrict__ Kb, u16* __restrict__ Vb) {
  const int bm = blockIdx.x * 128;
  const int bn = blockIdx.y * 128;
  const int tid = threadIdx.x;
  const int wid = tid >> 6;
  const int lr = tid & 15;
  const int lg = (tid >> 4) & 3;
  const int wr = wid >> 1, wc = wid & 1;

  __shared__ u16 Ald[128 * 64];
  __shared__ u16 Bld[128 * 64];

  f32x4 acc[4][4] = {};

  const u16* Ag = A + (size_t)bm * K;
  const u16* Bg = Bt + (size_t)bn * K;
  const int rowi = tid >> 3;  // 0..31
  const int blk = tid & 7;

  for (int kt = 0; kt < (K >> 6); ++kt) {
    const int kof = kt << 6;
#pragma unroll
    for (int i = 0; i < 4; ++i) {
      const int row = i * 32 + rowi;
      gload_lds16(Ag + (size_t)row * K + kof + blk * 8,
                  &Ald[(i * 32 + wid * 8) * 64]);
      gload_lds16(Bg + (size_t)row * K + kof + blk * 8,
                  &Bld[(i * 32 + wid * 8) * 64]);
    }
    __syncthreads();
#pragma unroll
    for (int c = 0; c < 2; ++c) {
      bf16x8 af[4], bfr[4];
#pragma unroll
      for (int t = 0; t < 4; ++t)
        af[t] = *(const bf16x8*)&Ald[(wr * 64 + t * 16 + lr) * 64 + c * 32 + lg * 8];
#pragma unroll
      for (int t = 0; t < 4; ++t)
        bfr[t] = *(const bf16x8*)&Bld[(wc * 64 + t * 16 + lr) * 64 + c * 32 + lg * 8];
#pragma unroll
      for (int mt = 0; mt < 4; ++mt)
#pragma unroll
        for (int nt = 0; nt < 4; ++nt)
          acc[mt][nt] = __builtin_amdgcn_mfma_f32_16x16x32_bf16(
              af[mt], bfr[nt], acc[mt][nt], 0, 0, 0);
    }
    __syncthreads();
  }

#pragma unroll
  for (int mt = 0; mt < 4; ++mt) {
    const int row0 = bm + wr * 64 + mt * 16 + lg * 4;
#pragma unroll
    for (int nt = 0; nt < 4; ++nt) {
      const int col = bn + wc * 64 + nt * 16 + lr;
      const float bv = bias[col];
#pragma unroll
      for (int r = 0; r < 4; ++r) {
        float v = acc[mt][nt][r] + bv;
        const int rr = row0 + r;
        if (MODE == 0) {
          const int which = col >> 10;
          const int h = (col >> 6) & 15;
          const int d = col & 63;
          const int b = rr >> 11;
          const int n = rr & 2047;
          const size_t idx = (((size_t)(b * 16 + h)) * 2048 + n) * 64 + d;
          if (which == 0)
            Qb[idx] = f2bf(v * 0.125f);
          else if (which == 1)
            Kb[idx] = f2bf(v);
          else
            Vb[idx] = f2bf(v);
        } else {
          outF[(size_t)rr * N + col] = v;
        }
      }
    }
  }
}

// ---------------- flash attention ----------------
// Q,K: [bh][2048][64] bf16 (Q pre-scaled), Vt: [bh][64][2048] bf16
// AO: [b][2048][1024] bf16
__global__ __launch_bounds__(256) void flash_attn(const u16* __restrict__ Qb,
                                                  const u16* __restrict__ Kb,
                                                  const u16* __restrict__ Vt,
                                                  u16* __restrict__ AO) {
  const int qt = blockIdx.x;  // 0..31
  const int bh = blockIdx.y;  // 0..31
  const int tid = threadIdx.x;
  const int w = tid >> 6;
  const int lane = tid & 63;
  const int lr = lane & 15;
  const int lg = lane >> 4;

  __shared__ u16 Kld[64 * 64];     // [n][d], blocks xor-swizzled by (n&7)
  __shared__ u16 Vld[64 * 64];     // [d][n], blocks xor-swizzled by (d&7)
  __shared__ u16 Pld[4][16 * 72];  // per-wave P tile, padded to 72 (16B-aligned rows)

  // Q fragments (A-operand), direct from global
  const size_t qbase = ((size_t)bh * 2048 + qt * 64 + w * 16 + lr) * 64;
  bf16x8 qf[2];
  qf[0] = *(const bf16x8*)&Qb[qbase + lg * 8];
  qf[1] = *(const bf16x8*)&Qb[qbase + 32 + lg * 8];

  f32x4 acc[4] = {};
  float mrow[4], lsum[4];
#pragma unroll
  for (int r = 0; r < 4; ++r) { mrow[r] = -1e30f; lsum[r] = 0.f; }

  const u16* Kg = Kb + (size_t)bh * 2048 * 64;
  const u16* Vg = Vt + (size_t)bh * 64 * 2048;
  const int rowi = tid >> 3;  // 0..31
  const int blk0 = tid & 7;

  for (int kt = 0; kt < 32; ++kt) {
#pragma unroll
    for (int i = 0; i < 2; ++i) {
      const int row = i * 32 + rowi;
      const int blk = blk0 ^ (row & 7);  // inverse-swizzled global source
      gload_lds16(Kg + ((size_t)(kt * 64 + row)) * 64 + blk * 8,
                  &Kld[(i * 32 + w * 8) * 64]);
      gload_lds16(Vg + (size_t)row * 2048 + kt * 64 + blk * 8,
                  &Vld[(i * 32 + w * 8) * 64]);
    }
    __syncthreads();

    // S = Q K^T  (16 q-rows x 64 k-cols per wave)
    f32x4 s[4];
#pragma unroll
    for (int nt = 0; nt < 4; ++nt) {
      const int n = nt * 16 + lr;
      const char* kbase = (const char*)Kld + n * 128;
      bf16x8 kf0 = *(const bf16x8*)(kbase + ((lg * 16) ^ ((n & 7) << 4)));
      bf16x8 kf1 = *(const bf16x8*)(kbase + ((lg * 16 + 64) ^ ((n & 7) << 4)));
      f32x4 z = {};
      z = __builtin_amdgcn_mfma_f32_16x16x32_bf16(qf[0], kf0, z, 0, 0, 0);
      s[nt] = __builtin_amdgcn_mfma_f32_16x16x32_bf16(qf[1], kf1, z, 0, 0, 0);
    }

    // online softmax: lane covers rows 4*lg + r, cols nt*16+lr
#pragma unroll
    for (int r = 0; r < 4; ++r) {
      float mx = fmaxf(fmaxf(s[0][r], s[1][r]), fmaxf(s[2][r], s[3][r]));
      mx = fmaxf(mx, __shfl_xor(mx, 1, 64));
      mx = fmaxf(mx, __shfl_xor(mx, 2, 64));
      mx = fmaxf(mx, __shfl_xor(mx, 4, 64));
      mx = fmaxf(mx, __shfl_xor(mx, 8, 64));
      const float newm = fmaxf(mrow[r], mx);
      const float corr = __expf(mrow[r] - newm);
      mrow[r] = newm;
      float ps = 0.f;
#pragma unroll
      for (int nt = 0; nt < 4; ++nt) {
        float p = __expf(s[nt][r] - newm);
        s[nt][r] = p;
        ps += p;
      }
      ps += __shfl_xor(ps, 1, 64);
      ps += __shfl_xor(ps, 2, 64);
      ps += __shfl_xor(ps, 4, 64);
      ps += __shfl_xor(ps, 8, 64);
      lsum[r] = lsum[r] * corr + ps;
#pragma unroll
      for (int dt = 0; dt < 4; ++dt) acc[dt][r] *= corr;
    }

    // P -> LDS (bf16), then consume as A-fragments (same wave only)
#pragma unroll
    for (int r = 0; r < 4; ++r)
#pragma unroll
      for (int nt = 0; nt < 4; ++nt)
        Pld[w][(4 * lg + r) * 72 + nt * 16 + lr] = f2bf(s[nt][r]);

#pragma unroll
    for (int c = 0; c < 2; ++c) {
      bf16x8 pf = *(const bf16x8*)&Pld[w][lr * 72 + c * 32 + lg * 8];
#pragma unroll
      for (int dt = 0; dt < 4; ++dt) {
        const int drow = dt * 16 + lr;
        bf16x8 vf = *(const bf16x8*)((const char*)Vld + drow * 128 +
                                     ((lg * 16 + c * 64) ^ ((drow & 7) << 4)));
        acc[dt] = __builtin_amdgcn_mfma_f32_16x16x32_bf16(pf, vf, acc[dt], 0, 0, 0);
      }
    }
    __syncthreads();
  }

  // epilogue: AO[b][n][h*64 + d]
  const int b = bh >> 4, h = bh & 15;
#pragma unroll
  for (int dt = 0; dt < 4; ++dt) {
#pragma unroll
    for (int r = 0; r < 4; ++r) {
      const int n = qt * 64 + w * 16 + 4 * lg + r;
      const int cc = h * 64 + dt * 16 + lr;
      const float v = acc[dt][r] / lsum[r];
      AO[((size_t)b * 2048 + n) * 1024 + cc] = f2bf(v);
    }
  }
}

// ---------------- launch ----------------
extern "C" void kernel_launch(void* const* d_in, const int* in_sizes, int n_in,
                              void* d_out, int out_size, void* d_ws, size_t ws_size,
                              hipStream_t stream) {
  const float* x = (const float*)d_in[0];
  const float* w_qkv = (const float*)d_in[1];
  const float* b_qkv = (const float*)d_in[2];
  const float* w_proj = (const float*)d_in[3];
  const float* b_proj = (const float*)d_in[4];
  float* out = (float*)d_out;

  char* ws = (char*)d_ws;
  u16* xb = (u16*)(ws);                          // 8 MiB  [4096][1024]
  u16* wqT = (u16*)(ws + (8ull << 20));          // 6 MiB  [3072][1024]
  u16* wpT = (u16*)(ws + (14ull << 20));         // 2 MiB  [1024][1024]
  u16* Qb = (u16*)(ws + (16ull << 20));          // 8 MiB  [32][2048][64]
  u16* Kb = (u16*)(ws + (24ull << 20));          // 8 MiB
  u16* Vb = (u16*)(ws + (32ull << 20));          // 8 MiB
  u16* Vt = (u16*)(ws + (40ull << 20));          // 8 MiB  [32][64][2048]
  u16* AO = (u16*)(ws + (48ull << 20));          // 8 MiB  [4096][1024]

  cvt_bf16<<<dim3(2048), dim3(256), 0, stream>>>(x, xb, 4194304);
  trans_w<<<dim3(16, 48), dim3(256), 0, stream>>>(w_qkv, wqT, 1024, 3072);
  trans_w<<<dim3(16, 16), dim3(256), 0, stream>>>(w_proj, wpT, 1024, 1024);
  gemm_bt<0><<<dim3(32, 24), dim3(256), 0, stream>>>(xb, wqT, 4096, 3072, 1024,
                                                     b_qkv, nullptr, Qb, Kb, Vb);
  v_trans<<<dim3(32, 32), dim3(256), 0, stream>>>(Vb, Vt);
  flash_attn<<<dim3(32, 32), dim3(256), 0, stream>>>(Qb, Kb, Vt, AO);
  gemm_bt<1><<<dim3(32, 8), dim3(256), 0, stream>>>(AO, wpT, 4096, 1024, 1024,
                                                    b_proj, out, nullptr, nullptr,
                                                    nullptr);
}

// Round 2
// 162.862 us; speedup vs baseline: 1.2772x; 1.2772x over previous
//
#include <hip/hip_runtime.h>

// Requires ws_size >= 56 MiB.
typedef short bf16x8 __attribute__((ext_vector_type(8)));
typedef float f32x4 __attribute__((ext_vector_type(4)));
typedef float f32x16 __attribute__((ext_vector_type(16)));
typedef unsigned short ushort8 __attribute__((ext_vector_type(8)));
typedef unsigned short ushort4v __attribute__((ext_vector_type(4)));
typedef unsigned int uint4v __attribute__((ext_vector_type(4)));
typedef unsigned short u16;

__device__ inline u16 f2bf(float f) {
  unsigned int u = __float_as_uint(f);
  u += 0x7fffu + ((u >> 16) & 1u);
  return (u16)(u >> 16);
}

__device__ inline unsigned cvt_pk_bf16(float lo, float hi2) {
  unsigned r;
  asm("v_cvt_pk_bf16_f32 %0, %1, %2" : "=v"(r) : "v"(lo), "v"(hi2));
  return r;
}

__device__ inline void perm32swap(unsigned& a, unsigned& b) {
  asm("v_permlane32_swap_b32 %0, %1" : "+v"(a), "+v"(b));
}

__device__ inline void gload_lds16(const u16* g, u16* l) {
  __builtin_amdgcn_global_load_lds(
      (const __attribute__((address_space(1))) unsigned int*)g,
      (__attribute__((address_space(3))) unsigned int*)l, 16, 0, 0);
}

// ---------------- elementwise f32 -> bf16 ----------------
__global__ __launch_bounds__(256) void cvt_bf16(const float* __restrict__ in,
                                                u16* __restrict__ out, int n) {
  int i = (blockIdx.x * 256 + threadIdx.x) * 8;
  if (i >= n) return;
  float4 a = *(const float4*)(in + i);
  float4 b = *(const float4*)(in + i + 4);
  ushort8 o;
  o[0] = f2bf(a.x); o[1] = f2bf(a.y); o[2] = f2bf(a.z); o[3] = f2bf(a.w);
  o[4] = f2bf(b.x); o[5] = f2bf(b.y); o[6] = f2bf(b.z); o[7] = f2bf(b.w);
  *(ushort8*)(out + i) = o;
}

// ---------------- W[K][N] f32 -> Wt[N][K] bf16 ----------------
__global__ __launch_bounds__(256) void trans_w(const float* __restrict__ W,
                                               u16* __restrict__ Wt, int K, int N) {
  const int k0 = blockIdx.x * 64, n0 = blockIdx.y * 64;
  const int tx = threadIdx.x & 63, ty = threadIdx.x >> 6;
  __shared__ float t[64][65];
#pragma unroll
  for (int i = 0; i < 16; ++i) {
    int r = i * 4 + ty;
    t[r][tx] = W[(size_t)(k0 + r) * N + n0 + tx];
  }
  __syncthreads();
#pragma unroll
  for (int i = 0; i < 16; ++i) {
    int r = i * 4 + ty;
    Wt[(size_t)(n0 + r) * K + k0 + tx] = f2bf(t[tx][r]);
  }
}

// ---------------- V[bh][2048][64] -> Vt[bh][64][2048] (bf16) ----------------
__global__ __launch_bounds__(256) void v_trans(const u16* __restrict__ V,
                                               u16* __restrict__ Vt) {
  const int bh = blockIdx.y;
  const int n0 = blockIdx.x * 64;
  const int tid = threadIdx.x;
  __shared__ u16 t[64][68];
  const u16* src = V + ((size_t)bh * 2048 + n0) * 64;
  u16* dst = Vt + (size_t)bh * 64 * 2048;
#pragma unroll
  for (int i = 0; i < 2; ++i) {
    int r = i * 32 + (tid >> 3);
    int blk = tid & 7;
    ushort8 val = *(const ushort8*)&src[(size_t)r * 64 + blk * 8];
#pragma unroll
    for (int j = 0; j < 8; ++j) t[r][blk * 8 + j] = val[j];
  }
  __syncthreads();
#pragma unroll
  for (int i = 0; i < 2; ++i) {
    int d = i * 32 + (tid >> 3);
    int nb = tid & 7;
    ushort8 val;
#pragma unroll
    for (int j = 0; j < 8; ++j) val[j] = t[nb * 8 + j][d];
    *(ushort8*)&dst[(size_t)d * 2048 + n0 + nb * 8] = val;
  }
}

// ---------------- GEMM: C[M][N] = A[M][K] * Bt[N][K]^T  (m97 128^2 structure) ----
template <int MODE>
__global__ __launch_bounds__(256) void gemm_bt(
    const u16* __restrict__ A, const u16* __restrict__ Bt, int M, int N, int K,
    const float* __restrict__ bias, float* __restrict__ outF,
    u16* __restrict__ Qb, u16* __restrict__ Kb, u16* __restrict__ Vb) {
  const int bm = blockIdx.x * 128;
  const int bn = blockIdx.y * 128;
  const int tid = threadIdx.x;
  const int wid = tid >> 6;
  const int lr = tid & 15;
  const int lg = (tid >> 4) & 3;
  const int wr = wid >> 1, wc = wid & 1;

  __shared__ u16 Ald[128 * 64];
  __shared__ u16 Bld[128 * 64];

  f32x4 acc[4][4] = {};

  const u16* Ag = A + (size_t)bm * K;
  const u16* Bg = Bt + (size_t)bn * K;
  const int rowi = tid >> 3;
  const int blk = tid & 7;

  for (int kt = 0; kt < (K >> 6); ++kt) {
    const int kof = kt << 6;
#pragma unroll
    for (int i = 0; i < 4; ++i) {
      const int row = i * 32 + rowi;
      gload_lds16(Ag + (size_t)row * K + kof + blk * 8,
                  &Ald[(i * 32 + wid * 8) * 64]);
      gload_lds16(Bg + (size_t)row * K + kof + blk * 8,
                  &Bld[(i * 32 + wid * 8) * 64]);
    }
    __syncthreads();
#pragma unroll
    for (int c = 0; c < 2; ++c) {
      bf16x8 af[4], bfr[4];
#pragma unroll
      for (int t = 0; t < 4; ++t)
        af[t] = *(const bf16x8*)&Ald[(wr * 64 + t * 16 + lr) * 64 + c * 32 + lg * 8];
#pragma unroll
      for (int t = 0; t < 4; ++t)
        bfr[t] = *(const bf16x8*)&Bld[(wc * 64 + t * 16 + lr) * 64 + c * 32 + lg * 8];
#pragma unroll
      for (int mt = 0; mt < 4; ++mt)
#pragma unroll
        for (int nt = 0; nt < 4; ++nt)
          acc[mt][nt] = __builtin_amdgcn_mfma_f32_16x16x32_bf16(
              af[mt], bfr[nt], acc[mt][nt], 0, 0, 0);
    }
    __syncthreads();
  }

#pragma unroll
  for (int mt = 0; mt < 4; ++mt) {
    const int row0 = bm + wr * 64 + mt * 16 + lg * 4;
#pragma unroll
    for (int nt = 0; nt < 4; ++nt) {
      const int col = bn + wc * 64 + nt * 16 + lr;
      const float bv = bias[col];
#pragma unroll
      for (int r = 0; r < 4; ++r) {
        float v = acc[mt][nt][r] + bv;
        const int rr = row0 + r;
        if (MODE == 0) {
          const int which = col >> 10;
          const int h = (col >> 6) & 15;
          const int d = col & 63;
          const int b = rr >> 11;
          const int n = rr & 2047;
          const size_t idx = (((size_t)(b * 16 + h)) * 2048 + n) * 64 + d;
          if (which == 0)
            Qb[idx] = f2bf(v * 0.125f);
          else if (which == 1)
            Kb[idx] = f2bf(v);
          else
            Vb[idx] = f2bf(v);
        } else {
          outF[(size_t)rr * N + col] = v;
        }
      }
    }
  }
}

// ---------------- flash attention v2: 8-warp, 32x32 MFMA, swapped operands ----
// Q,K: [bh][2048][64] bf16 (Q pre-scaled), Vt: [bh][64][2048] bf16
// AO: [b][2048][1024] bf16
// Per warp: 32 q-rows. S^T = mfma(K, Q): lane holds P[q=lane&31][k-slice] in regs.
// O^T = mfma(Vt, P^T): col = q, so softmax stats/rescale are lane-local scalars.
__global__ __launch_bounds__(512, 2) void flash_attn2(const u16* __restrict__ Qb,
                                                      const u16* __restrict__ Kb,
                                                      const u16* __restrict__ Vt,
                                                      u16* __restrict__ AO) {
  const int bh = blockIdx.x & 31;   // co-resident blocks on an XCD share bh
  const int qt = blockIdx.x >> 5;
  const int tid = threadIdx.x;
  const int w = tid >> 6;
  const int lane = tid & 63;
  const int lq = lane & 31;
  const int hi = lane >> 5;
  const int q0 = qt * 256 + w * 32;

  __shared__ u16 Kld[2][64 * 64];
  __shared__ u16 Vld[2][64 * 64];

  // Q fragments (B-operand of swapped QK^T): Q[q0+lq][16t + 8hi + j]
  const u16* Qg = Qb + ((size_t)bh * 2048 + q0 + lq) * 64 + 8 * hi;
  bf16x8 qf[4];
#pragma unroll
  for (int t = 0; t < 4; ++t) qf[t] = *(const bf16x8*)(Qg + 16 * t);

  f32x16 ot0 = {}, ot1 = {};
  float m = -1e30f, lsum = 0.f;

  const u16* Kg = Kb + (size_t)bh * (2048 * 64);
  const u16* Vg = Vt + (size_t)bh * (64 * 2048);
  const int srow = tid >> 3;                    // 0..63
  const int sslot = (tid & 7) ^ (srow & 7);     // pre-swizzled source slot
  const size_t ksrc0 = (size_t)srow * 64 + sslot * 8;
  const size_t vsrc0 = (size_t)srow * 2048 + sslot * 8;

  auto stage = [&](int buf, int kt) {
    gload_lds16(Kg + (size_t)kt * 4096 + ksrc0, &Kld[buf][w * 8 * 64]);
    gload_lds16(Vg + (size_t)kt * 64 + vsrc0, &Vld[buf][w * 8 * 64]);
  };

  stage(0, 0);
  __syncthreads();

  const float LOG2E = 1.44269504f;

  for (int kt = 0; kt < 32; ++kt) {
    const int cur = kt & 1;
    if (kt < 31) stage(cur ^ 1, kt + 1);

    // ---- S^T[k][q] = sum_d K[k][d] Q[q][d], two 32-k tiles ----
    const char* kbase = (const char*)&Kld[cur][0];
    f32x16 sa = {}, sb = {};
#pragma unroll
    for (int t = 0; t < 4; ++t) {
      const int r0 = lq, r1 = 32 + lq;
      const int csel = (32 * t + 16 * hi) ^ ((lq & 7) << 4);
      bf16x8 kf0 = *(const bf16x8*)(kbase + r0 * 128 + csel);
      bf16x8 kf1 = *(const bf16x8*)(kbase + r1 * 128 + csel);
      sa = __builtin_amdgcn_mfma_f32_32x32x16_bf16(kf0, qf[t], sa, 0, 0, 0);
      sb = __builtin_amdgcn_mfma_f32_32x32x16_bf16(kf1, qf[t], sb, 0, 0, 0);
    }

    // ---- online softmax for q = lq (lane pair l, l^32 hold complementary k) --
    float tmax[8];
#pragma unroll
    for (int r = 0; r < 8; ++r)
      tmax[r] = fmaxf(fmaxf(sa[r], sa[r + 8]), fmaxf(sb[r], sb[r + 8]));
#pragma unroll
    for (int st = 4; st > 0; st >>= 1)
#pragma unroll
      for (int r = 0; r < st; ++r) tmax[r] = fmaxf(tmax[r], tmax[r + st]);
    float pmax = fmaxf(tmax[0], __shfl_xor(tmax[0], 32, 64));

    if (__any(pmax > m + 8.0f)) {   // defer-max (T13)
      const float newm = fmaxf(m, pmax);
      const float corr = exp2f((m - newm) * LOG2E);
      m = newm;
      lsum *= corr;
#pragma unroll
      for (int r = 0; r < 16; ++r) { ot0[r] *= corr; ot1[r] *= corr; }
    }

    const float mk = m * LOG2E;
#pragma unroll
    for (int r = 0; r < 16; ++r) {
      sa[r] = exp2f(fmaf(sa[r], LOG2E, -mk));
      sb[r] = exp2f(fmaf(sb[r], LOG2E, -mk));
    }

    float tsum[8];
#pragma unroll
    for (int r = 0; r < 8; ++r)
      tsum[r] = (sa[r] + sa[r + 8]) + (sb[r] + sb[r + 8]);
#pragma unroll
    for (int st = 4; st > 0; st >>= 1)
#pragma unroll
      for (int r = 0; r < st; ++r) tsum[r] += tsum[r + st];
    lsum += tsum[0] + __shfl_xor(tsum[0], 32, 64);

    // ---- P -> bf16 PV B-fragments in-register (cvt_pk + permlane32_swap) ----
    unsigned Ua[8], Ub[8];  // U[s][m2]: k-pair (8s + 4hi + 2m2, +1)
#pragma unroll
    for (int s = 0; s < 4; ++s)
#pragma unroll
      for (int m2 = 0; m2 < 2; ++m2) {
        Ua[s * 2 + m2] = cvt_pk_bf16(sa[4 * s + 2 * m2], sa[4 * s + 2 * m2 + 1]);
        Ub[s * 2 + m2] = cvt_pk_bf16(sb[4 * s + 2 * m2], sb[4 * s + 2 * m2 + 1]);
      }
    bf16x8 pfrag[4];
#pragma unroll
    for (int t = 0; t < 4; ++t) {
      const unsigned* U = (t < 2) ? Ua : Ub;
      const int tt = t & 1;
      unsigned w0 = U[(2 * tt) * 2 + 0], w2 = U[(2 * tt + 1) * 2 + 0];
      unsigned w1 = U[(2 * tt) * 2 + 1], w3 = U[(2 * tt + 1) * 2 + 1];
      perm32swap(w0, w2);
      perm32swap(w1, w3);
      uint4v uu = {w0, w1, w2, w3};
      pfrag[t] = __builtin_bit_cast(bf16x8, uu);
    }

    // ---- O^T[d][q] += Vt[d][k] P^T[k][q] ----
    const char* vbase = (const char*)&Vld[cur][0];
#pragma unroll
    for (int t = 0; t < 4; ++t) {
      const int r0 = lq, r1 = 32 + lq;
      const int csel = (32 * t + 16 * hi) ^ ((lq & 7) << 4);
      bf16x8 vf0 = *(const bf16x8*)(vbase + r0 * 128 + csel);
      bf16x8 vf1 = *(const bf16x8*)(vbase + r1 * 128 + csel);
      ot0 = __builtin_amdgcn_mfma_f32_32x32x16_bf16(vf0, pfrag[t], ot0, 0, 0, 0);
      ot1 = __builtin_amdgcn_mfma_f32_32x32x16_bf16(vf1, pfrag[t], ot1, 0, 0, 0);
    }
    __syncthreads();
  }

  // ---- epilogue: O[q][d] = O^T[d][q] / lsum ----
  const float inv = 1.0f / lsum;
  const int b = bh >> 4, h = bh & 15;
  u16* Ao = AO + ((size_t)(b * 2048 + q0 + lq)) * 1024 + h * 64;
#pragma unroll
  for (int s = 0; s < 4; ++s) {
    {
      const int d = 8 * s + 4 * hi;
      ushort4v pk;
#pragma unroll
      for (int i = 0; i < 4; ++i) pk[i] = f2bf(ot0[4 * s + i] * inv);
      *(ushort4v*)(Ao + d) = pk;
    }
    {
      const int d = 32 + 8 * s + 4 * hi;
      ushort4v pk;
#pragma unroll
      for (int i = 0; i < 4; ++i) pk[i] = f2bf(ot1[4 * s + i] * inv);
      *(ushort4v*)(Ao + d) = pk;
    }
  }
}

// ---------------- launch ----------------
extern "C" void kernel_launch(void* const* d_in, const int* in_sizes, int n_in,
                              void* d_out, int out_size, void* d_ws, size_t ws_size,
                              hipStream_t stream) {
  const float* x = (const float*)d_in[0];
  const float* w_qkv = (const float*)d_in[1];
  const float* b_qkv = (const float*)d_in[2];
  const float* w_proj = (const float*)d_in[3];
  const float* b_proj = (const float*)d_in[4];
  float* out = (float*)d_out;

  char* ws = (char*)d_ws;
  u16* xb = (u16*)(ws);                          // 8 MiB  [4096][1024]
  u16* wqT = (u16*)(ws + (8ull << 20));          // 6 MiB  [3072][1024]
  u16* wpT = (u16*)(ws + (14ull << 20));         // 2 MiB  [1024][1024]
  u16* Qb = (u16*)(ws + (16ull << 20));          // 8 MiB  [32][2048][64]
  u16* Kb = (u16*)(ws + (24ull << 20));          // 8 MiB
  u16* Vb = (u16*)(ws + (32ull << 20));          // 8 MiB
  u16* Vt = (u16*)(ws + (40ull << 20));          // 8 MiB  [32][64][2048]
  u16* AO = (u16*)(ws + (48ull << 20));          // 8 MiB  [4096][1024]

  cvt_bf16<<<dim3(2048), dim3(256), 0, stream>>>(x, xb, 4194304);
  trans_w<<<dim3(16, 48), dim3(256), 0, stream>>>(w_qkv, wqT, 1024, 3072);
  trans_w<<<dim3(16, 16), dim3(256), 0, stream>>>(w_proj, wpT, 1024, 1024);
  gemm_bt<0><<<dim3(32, 24), dim3(256), 0, stream>>>(xb, wqT, 4096, 3072, 1024,
                                                     b_qkv, nullptr, Qb, Kb, Vb);
  v_trans<<<dim3(32, 32), dim3(256), 0, stream>>>(Vb, Vt);
  flash_attn2<<<dim3(256), dim3(512), 0, stream>>>(Qb, Kb, Vt, AO);
  gemm_bt<1><<<dim3(32, 8), dim3(256), 0, stream>>>(AO, wpT, 4096, 1024, 1024,
                                                    b_proj, out, nullptr, nullptr,
                                                    nullptr);
}

// Round 3
// 157.096 us; speedup vs baseline: 1.3241x; 1.0367x over previous
//
#include <hip/hip_runtime.h>

// Requires ws_size >= 48 MiB.
typedef short bf16x8 __attribute__((ext_vector_type(8)));
typedef float f32x4 __attribute__((ext_vector_type(4)));
typedef float f32x16 __attribute__((ext_vector_type(16)));
typedef unsigned short ushort8 __attribute__((ext_vector_type(8)));
typedef unsigned short ushort4v __attribute__((ext_vector_type(4)));
typedef unsigned int uint4v __attribute__((ext_vector_type(4)));
typedef unsigned short u16;

__device__ inline u16 f2bf(float f) {
  unsigned int u = __float_as_uint(f);
  u += 0x7fffu + ((u >> 16) & 1u);
  return (u16)(u >> 16);
}

__device__ inline unsigned cvt_pk_bf16(float lo, float hi2) {
  unsigned r;
  asm("v_cvt_pk_bf16_f32 %0, %1, %2" : "=v"(r) : "v"(lo), "v"(hi2));
  return r;
}

__device__ inline void perm32swap(unsigned& a, unsigned& b) {
  asm("v_permlane32_swap_b32 %0, %1" : "+v"(a), "+v"(b));
}

__device__ inline void gload_lds16(const u16* g, u16* l) {
  __builtin_amdgcn_global_load_lds(
      (const __attribute__((address_space(1))) unsigned int*)g,
      (__attribute__((address_space(3))) unsigned int*)l, 16, 0, 0);
}

// ---------------- elementwise f32 -> bf16 ----------------
__global__ __launch_bounds__(256) void cvt_bf16(const float* __restrict__ in,
                                                u16* __restrict__ out, int n) {
  int i = (blockIdx.x * 256 + threadIdx.x) * 8;
  if (i >= n) return;
  float4 a = *(const float4*)(in + i);
  float4 b = *(const float4*)(in + i + 4);
  ushort8 o;
  o[0] = f2bf(a.x); o[1] = f2bf(a.y); o[2] = f2bf(a.z); o[3] = f2bf(a.w);
  o[4] = f2bf(b.x); o[5] = f2bf(b.y); o[6] = f2bf(b.z); o[7] = f2bf(b.w);
  *(ushort8*)(out + i) = o;
}

// ---------------- W[K][N] f32 -> Wt[N][K] bf16 ----------------
__global__ __launch_bounds__(256) void trans_w(const float* __restrict__ W,
                                               u16* __restrict__ Wt, int K, int N) {
  const int k0 = blockIdx.x * 64, n0 = blockIdx.y * 64;
  const int tx = threadIdx.x & 63, ty = threadIdx.x >> 6;
  __shared__ float t[64][65];
#pragma unroll
  for (int i = 0; i < 16; ++i) {
    int r = i * 4 + ty;
    t[r][tx] = W[(size_t)(k0 + r) * N + n0 + tx];
  }
  __syncthreads();
#pragma unroll
  for (int i = 0; i < 16; ++i) {
    int r = i * 4 + ty;
    Wt[(size_t)(n0 + r) * K + k0 + tx] = f2bf(t[tx][r]);
  }
}

// ---------------- GEMM: C[M][N] = A[M][K] * Bt[N][K]^T  (m97 128^2 structure) ----
// MODE 0: epilogue + bias -> Q [bh][n][64] scaled; K,V fragment-packed
// MODE 1: epilogue + bias -> f32 out
template <int MODE>
__global__ __launch_bounds__(256) void gemm_bt(
    const u16* __restrict__ A, const u16* __restrict__ Bt, int M, int N, int K,
    const float* __restrict__ bias, float* __restrict__ outF,
    u16* __restrict__ Qb, u16* __restrict__ Kb, u16* __restrict__ Vb) {
  const int bm = blockIdx.x * 128;
  const int bn = blockIdx.y * 128;
  const int tid = threadIdx.x;
  const int wid = tid >> 6;
  const int lr = tid & 15;
  const int lg = (tid >> 4) & 3;
  const int wr = wid >> 1, wc = wid & 1;

  __shared__ u16 Ald[128 * 64];
  __shared__ u16 Bld[128 * 64];

  f32x4 acc[4][4] = {};

  const u16* Ag = A + (size_t)bm * K;
  const u16* Bg = Bt + (size_t)bn * K;
  const int rowi = tid >> 3;
  const int blk = tid & 7;

  for (int kt = 0; kt < (K >> 6); ++kt) {
    const int kof = kt << 6;
#pragma unroll
    for (int i = 0; i < 4; ++i) {
      const int row = i * 32 + rowi;
      gload_lds16(Ag + (size_t)row * K + kof + blk * 8,
                  &Ald[(i * 32 + wid * 8) * 64]);
      gload_lds16(Bg + (size_t)row * K + kof + blk * 8,
                  &Bld[(i * 32 + wid * 8) * 64]);
    }
    __syncthreads();
#pragma unroll
    for (int c = 0; c < 2; ++c) {
      bf16x8 af[4], bfr[4];
#pragma unroll
      for (int t = 0; t < 4; ++t)
        af[t] = *(const bf16x8*)&Ald[(wr * 64 + t * 16 + lr) * 64 + c * 32 + lg * 8];
#pragma unroll
      for (int t = 0; t < 4; ++t)
        bfr[t] = *(const bf16x8*)&Bld[(wc * 64 + t * 16 + lr) * 64 + c * 32 + lg * 8];
#pragma unroll
      for (int mt = 0; mt < 4; ++mt)
#pragma unroll
        for (int nt = 0; nt < 4; ++nt)
          acc[mt][nt] = __builtin_amdgcn_mfma_f32_16x16x32_bf16(
              af[mt], bfr[nt], acc[mt][nt], 0, 0, 0);
    }
    __syncthreads();
  }

#pragma unroll
  for (int mt = 0; mt < 4; ++mt) {
    const int row0 = bm + wr * 64 + mt * 16 + lg * 4;
#pragma unroll
    for (int nt = 0; nt < 4; ++nt) {
      const int col = bn + wc * 64 + nt * 16 + lr;
      const float bv = bias[col];
#pragma unroll
      for (int r = 0; r < 4; ++r) {
        float v = acc[mt][nt][r] + bv;
        const int rr = row0 + r;
        if (MODE == 0) {
          const int which = col >> 10;
          const int h = (col >> 6) & 15;
          const int d = col & 63;
          const int b = rr >> 11;
          const int n = rr & 2047;
          const int bh = b * 16 + h;
          if (which == 0) {
            Qb[((size_t)bh * 2048 + n) * 64 + d] = f2bf(v * 0.125f);
          } else if (which == 1) {
            // fragment-packed K: frag s = 2t + rtile holds
            // K[kt*64 + rtile*32 + lq][16t + 8hi + j] at lane hi*32+lq
            const int kt2 = n >> 6, w6 = n & 63;
            const int rtile = w6 >> 5, lq = w6 & 31;
            const int t = d >> 4, h2 = (d >> 3) & 1, j = d & 7;
            const size_t idx =
                ((((size_t)bh * 32 + kt2) * 8 + t * 2 + rtile) * 64 + h2 * 32 + lq) * 8 + j;
            Kb[idx] = f2bf(v);
          } else {
            // fragment-packed V: frag s = 2t + dtile holds
            // V[kt*64 + 16t + 8hi + j][dtile*32 + lq] at lane hi*32+lq
            const int kt2 = n >> 6, nw = n & 63;
            const int t = nw >> 4, h2 = (nw >> 3) & 1, j = nw & 7;
            const int dtile = d >> 5, lq = d & 31;
            const size_t idx =
                ((((size_t)bh * 32 + kt2) * 8 + t * 2 + dtile) * 64 + h2 * 32 + lq) * 8 + j;
            Vb[idx] = f2bf(v);
          }
        } else {
          outF[(size_t)rr * N + col] = v;
        }
      }
    }
  }
}

// ---------------- flash attention v3: barrier-free, LDS-free, reg-resident ----
// Qb: [bh][2048][64] bf16 (pre-scaled). Kp/Vp: fragment-packed
// [bh][kt=32][s=8][lane=64][8] bf16. AO: [b][2048][1024] bf16.
// Per wave: 32 q-rows, swapped operands: S^T = mfma(K,Q), O^T = mfma(V,P^T).
// All 8 waves of a block read the same K/V fragments -> L1/L2 hits; no LDS,
// no __syncthreads: waves free-run, MFMA/VALU overlap across the 2 waves/SIMD.
__global__ __launch_bounds__(512, 2) void flash_attn3(const u16* __restrict__ Qb,
                                                      const u16* __restrict__ Kp,
                                                      const u16* __restrict__ Vp,
                                                      u16* __restrict__ AO) {
  const int bh = blockIdx.x & 31;   // blocks sharing bh land on the same XCD (%8)
  const int qt = blockIdx.x >> 5;
  const int tid = threadIdx.x;
  const int w = tid >> 6;
  const int lane = tid & 63;
  const int lq = lane & 31;
  const int hi = lane >> 5;
  const int q0 = qt * 256 + w * 32;

  // Q fragments (B-operand of swapped QK^T)
  const u16* Qg = Qb + ((size_t)bh * 2048 + q0 + lq) * 64 + 8 * hi;
  bf16x8 qf[4];
#pragma unroll
  for (int t = 0; t < 4; ++t) qf[t] = *(const bf16x8*)(Qg + 16 * t);

  const u16* Kg = Kp + (size_t)bh * (32 * 4096) + lane * 8;
  const u16* Vg = Vp + (size_t)bh * (32 * 4096) + lane * 8;

  f32x16 ot0 = {}, ot1 = {};
  float m = -1e30f, lsum = 0.f;
  const float LOG2E = 1.44269504f;

  bf16x8 kbuf[8], vbuf[8];
#pragma unroll
  for (int s = 0; s < 8; ++s) kbuf[s] = *(const bf16x8*)(Kg + s * 512);

  for (int kt = 0; kt < 32; ++kt) {
    // issue V(kt) loads now; consumed after softmax (~500 cyc away)
#pragma unroll
    for (int s = 0; s < 8; ++s)
      vbuf[s] = *(const bf16x8*)(Vg + (size_t)kt * 4096 + s * 512);

    // ---- S^T[k][q] = sum_d K[k][d] Q[q][d] ----
    f32x16 sa = {}, sb = {};
    __builtin_amdgcn_s_setprio(1);
#pragma unroll
    for (int t = 0; t < 4; ++t) {
      sa = __builtin_amdgcn_mfma_f32_32x32x16_bf16(kbuf[2 * t], qf[t], sa, 0, 0, 0);
      sb = __builtin_amdgcn_mfma_f32_32x32x16_bf16(kbuf[2 * t + 1], qf[t], sb, 0, 0, 0);
    }
    __builtin_amdgcn_s_setprio(0);

    // prefetch K(kt+1) into kbuf (last use was above); hidden by softmax+PV
    if (kt < 31) {
#pragma unroll
      for (int s = 0; s < 8; ++s)
        kbuf[s] = *(const bf16x8*)(Kg + (size_t)(kt + 1) * 4096 + s * 512);
    }

    // ---- online softmax for q = lq (lanes l, l^32 hold complementary k) ----
    float tmax[8];
#pragma unroll
    for (int r = 0; r < 8; ++r)
      tmax[r] = fmaxf(fmaxf(sa[r], sa[r + 8]), fmaxf(sb[r], sb[r + 8]));
#pragma unroll
    for (int st = 4; st > 0; st >>= 1)
#pragma unroll
      for (int r = 0; r < st; ++r) tmax[r] = fmaxf(tmax[r], tmax[r + st]);
    float pmax = fmaxf(tmax[0], __shfl_xor(tmax[0], 32, 64));

    if (__any(pmax > m + 8.0f)) {   // defer-max (T13)
      const float newm = fmaxf(m, pmax);
      const float corr = exp2f((m - newm) * LOG2E);
      m = newm;
      lsum *= corr;
#pragma unroll
      for (int r = 0; r < 16; ++r) { ot0[r] *= corr; ot1[r] *= corr; }
    }

    const float mk = m * LOG2E;
#pragma unroll
    for (int r = 0; r < 16; ++r) {
      sa[r] = exp2f(fmaf(sa[r], LOG2E, -mk));
      sb[r] = exp2f(fmaf(sb[r], LOG2E, -mk));
    }

    float tsum[8];
#pragma unroll
    for (int r = 0; r < 8; ++r)
      tsum[r] = (sa[r] + sa[r + 8]) + (sb[r] + sb[r + 8]);
#pragma unroll
    for (int st = 4; st > 0; st >>= 1)
#pragma unroll
      for (int r = 0; r < st; ++r) tsum[r] += tsum[r + st];
    lsum += tsum[0] + __shfl_xor(tsum[0], 32, 64);

    // ---- P -> bf16 PV B-fragments in-register (cvt_pk + permlane32_swap) ----
    unsigned Ua[8], Ub[8];
#pragma unroll
    for (int s = 0; s < 4; ++s)
#pragma unroll
      for (int m2 = 0; m2 < 2; ++m2) {
        Ua[s * 2 + m2] = cvt_pk_bf16(sa[4 * s + 2 * m2], sa[4 * s + 2 * m2 + 1]);
        Ub[s * 2 + m2] = cvt_pk_bf16(sb[4 * s + 2 * m2], sb[4 * s + 2 * m2 + 1]);
      }
    bf16x8 pfrag[4];
#pragma unroll
    for (int t = 0; t < 4; ++t) {
      const unsigned* U = (t < 2) ? Ua : Ub;
      const int tt = t & 1;
      unsigned w0 = U[(2 * tt) * 2 + 0], w2 = U[(2 * tt + 1) * 2 + 0];
      unsigned w1 = U[(2 * tt) * 2 + 1], w3 = U[(2 * tt + 1) * 2 + 1];
      perm32swap(w0, w2);
      perm32swap(w1, w3);
      uint4v uu = {w0, w1, w2, w3};
      pfrag[t] = __builtin_bit_cast(bf16x8, uu);
    }

    // ---- O^T[d][q] += V^T[d][k] P^T[k][q] ----
    __builtin_amdgcn_s_setprio(1);
#pragma unroll
    for (int t = 0; t < 4; ++t) {
      ot0 = __builtin_amdgcn_mfma_f32_32x32x16_bf16(vbuf[2 * t], pfrag[t], ot0, 0, 0, 0);
      ot1 = __builtin_amdgcn_mfma_f32_32x32x16_bf16(vbuf[2 * t + 1], pfrag[t], ot1, 0, 0, 0);
    }
    __builtin_amdgcn_s_setprio(0);
  }

  // ---- epilogue: O[q][d] = O^T[d][q] / lsum ----
  const float inv = 1.0f / lsum;
  const int b = bh >> 4, h = bh & 15;
  u16* Ao = AO + ((size_t)(b * 2048 + q0 + lq)) * 1024 + h * 64;
#pragma unroll
  for (int s = 0; s < 4; ++s) {
    {
      const int d = 8 * s + 4 * hi;
      ushort4v pk;
#pragma unroll
      for (int i = 0; i < 4; ++i) pk[i] = f2bf(ot0[4 * s + i] * inv);
      *(ushort4v*)(Ao + d) = pk;
    }
    {
      const int d = 32 + 8 * s + 4 * hi;
      ushort4v pk;
#pragma unroll
      for (int i = 0; i < 4; ++i) pk[i] = f2bf(ot1[4 * s + i] * inv);
      *(ushort4v*)(Ao + d) = pk;
    }
  }
}

// ---------------- launch ----------------
extern "C" void kernel_launch(void* const* d_in, const int* in_sizes, int n_in,
                              void* d_out, int out_size, void* d_ws, size_t ws_size,
                              hipStream_t stream) {
  const float* x = (const float*)d_in[0];
  const float* w_qkv = (const float*)d_in[1];
  const float* b_qkv = (const float*)d_in[2];
  const float* w_proj = (const float*)d_in[3];
  const float* b_proj = (const float*)d_in[4];
  float* out = (float*)d_out;

  char* ws = (char*)d_ws;
  u16* xb = (u16*)(ws);                          // 8 MiB  [4096][1024]
  u16* wqT = (u16*)(ws + (8ull << 20));          // 6 MiB  [3072][1024]
  u16* wpT = (u16*)(ws + (14ull << 20));         // 2 MiB  [1024][1024]
  u16* Qb = (u16*)(ws + (16ull << 20));          // 8 MiB  [32][2048][64]
  u16* Kp = (u16*)(ws + (24ull << 20));          // 8 MiB  packed frags
  u16* Vp = (u16*)(ws + (32ull << 20));          // 8 MiB  packed frags
  u16* AO = (u16*)(ws + (40ull << 20));          // 8 MiB  [4096][1024]

  cvt_bf16<<<dim3(2048), dim3(256), 0, stream>>>(x, xb, 4194304);
  trans_w<<<dim3(16, 48), dim3(256), 0, stream>>>(w_qkv, wqT, 1024, 3072);
  trans_w<<<dim3(16, 16), dim3(256), 0, stream>>>(w_proj, wpT, 1024, 1024);
  gemm_bt<0><<<dim3(32, 24), dim3(256), 0, stream>>>(xb, wqT, 4096, 3072, 1024,
                                                     b_qkv, nullptr, Qb, Kp, Vp);
  flash_attn3<<<dim3(256), dim3(512), 0, stream>>>(Qb, Kp, Vp, AO);
  gemm_bt<1><<<dim3(32, 8), dim3(256), 0, stream>>>(AO, wpT, 4096, 1024, 1024,
                                                    b_proj, out, nullptr, nullptr,
                                                    nullptr);
}

// Round 4
// 128.743 us; speedup vs baseline: 1.6157x; 1.2202x over previous
//
#include <hip/hip_runtime.h>

// Requires ws_size >= 48 MiB.
typedef short bf16x8 __attribute__((ext_vector_type(8)));
typedef float f32x4 __attribute__((ext_vector_type(4)));
typedef float f32x16 __attribute__((ext_vector_type(16)));
typedef unsigned short ushort8 __attribute__((ext_vector_type(8)));
typedef unsigned short ushort4v __attribute__((ext_vector_type(4)));
typedef unsigned int uint4v __attribute__((ext_vector_type(4)));
typedef unsigned short u16;

__device__ inline u16 f2bf(float f) {
  unsigned int u = __float_as_uint(f);
  u += 0x7fffu + ((u >> 16) & 1u);
  return (u16)(u >> 16);
}

__device__ inline unsigned cvt_pk_bf16(float lo, float hi2) {
  unsigned r;
  asm("v_cvt_pk_bf16_f32 %0, %1, %2" : "=v"(r) : "v"(lo), "v"(hi2));
  return r;
}

__device__ inline void perm32swap(unsigned& a, unsigned& b) {
  asm("v_permlane32_swap_b32 %0, %1" : "+v"(a), "+v"(b));
}

__device__ inline void gload_lds16(const u16* g, u16* l) {
  __builtin_amdgcn_global_load_lds(
      (const __attribute__((address_space(1))) unsigned int*)g,
      (__attribute__((address_space(3))) unsigned int*)l, 16, 0, 0);
}

// ---------------- elementwise f32 -> bf16 ----------------
__global__ __launch_bounds__(256) void cvt_bf16(const float* __restrict__ in,
                                                u16* __restrict__ out, int n) {
  int i = (blockIdx.x * 256 + threadIdx.x) * 8;
  if (i >= n) return;
  float4 a = *(const float4*)(in + i);
  float4 b = *(const float4*)(in + i + 4);
  ushort8 o;
  o[0] = f2bf(a.x); o[1] = f2bf(a.y); o[2] = f2bf(a.z); o[3] = f2bf(a.w);
  o[4] = f2bf(b.x); o[5] = f2bf(b.y); o[6] = f2bf(b.z); o[7] = f2bf(b.w);
  *(ushort8*)(out + i) = o;
}

// ---------------- W[K][N] f32 -> Wt[N][K] bf16 ----------------
__global__ __launch_bounds__(256) void trans_w(const float* __restrict__ W,
                                               u16* __restrict__ Wt, int K, int N) {
  const int k0 = blockIdx.x * 64, n0 = blockIdx.y * 64;
  const int tx = threadIdx.x & 63, ty = threadIdx.x >> 6;
  __shared__ float t[64][65];
#pragma unroll
  for (int i = 0; i < 16; ++i) {
    int r = i * 4 + ty;
    t[r][tx] = W[(size_t)(k0 + r) * N + n0 + tx];
  }
  __syncthreads();
#pragma unroll
  for (int i = 0; i < 16; ++i) {
    int r = i * 4 + ty;
    Wt[(size_t)(n0 + r) * K + k0 + tx] = f2bf(t[tx][r]);
  }
}

// ---------------- GEMM: C[M][N] = A[M][K] * Bt[N][K]^T ----------------
// 2-phase pipelined (T3-min recipe): STAGE(next) issued before MFMA(cur),
// single vmcnt(0)+barrier per K-step -> load latency hidden under compute.
// LDS reads swizzled via pre-swizzled global source (rule #21).
// MODE 0 epilogue: LDS-bounce -> coalesced fragment-packed Q/K/V stores.
// MODE 1 epilogue: bias + f32 row-major out.
template <int MODE>
__global__ __launch_bounds__(256) void gemm_bt(
    const u16* __restrict__ A, const u16* __restrict__ Bt, int M, int N, int K,
    const float* __restrict__ bias, float* __restrict__ outF,
    u16* __restrict__ Qb, u16* __restrict__ Kb, u16* __restrict__ Vb) {
  const int bm = blockIdx.x * 128;
  const int bn = blockIdx.y * 128;
  const int tid = threadIdx.x;
  const int wid = tid >> 6;
  const int lr = tid & 15;
  const int lg = (tid >> 4) & 3;
  const int wr = wid >> 1, wc = wid & 1;

  __shared__ u16 smem[32768];  // 64 KiB: A dbuf [2][8192] + B dbuf [2][8192]
  u16* Ab0 = smem;
  u16* Ab1 = smem + 8192;
  u16* Bb0 = smem + 16384;
  u16* Bb1 = smem + 24576;

  f32x4 acc[4][4] = {};

  const int rowi = tid >> 3;                    // 0..31
  const int sslot = ((tid & 7) ^ (rowi & 7)) * 8;  // pre-swizzled source slot
  const u16* Ag = A + (size_t)bm * K;
  const u16* Bg = Bt + (size_t)bn * K;
  const int nkt = K >> 6;

  auto stage = [&](u16* Ad, u16* Bd, int kt) {
    const int kof = kt << 6;
#pragma unroll
    for (int i = 0; i < 4; ++i) {
      const int row = i * 32 + rowi;
      gload_lds16(Ag + (size_t)row * K + kof + sslot, Ad + (i * 32 + wid * 8) * 64);
      gload_lds16(Bg + (size_t)row * K + kof + sslot, Bd + (i * 32 + wid * 8) * 64);
    }
  };

  stage(Ab0, Bb0, 0);
  __syncthreads();

  for (int kt = 0; kt < nkt; ++kt) {
    const int p = kt & 1;
    const char* Ard = (const char*)(p ? Ab1 : Ab0);
    const char* Brd = (const char*)(p ? Bb1 : Bb0);
    bf16x8 af[4], bfr[4];
    // c = 0 fragments (swizzled read)
#pragma unroll
    for (int t = 0; t < 4; ++t) {
      const int ra = wr * 64 + t * 16 + lr;
      const int rb = wc * 64 + t * 16 + lr;
      af[t] = *(const bf16x8*)(Ard + ra * 128 + ((lg * 16) ^ ((ra & 7) << 4)));
      bfr[t] = *(const bf16x8*)(Brd + rb * 128 + ((lg * 16) ^ ((rb & 7) << 4)));
    }
    if (kt + 1 < nkt) stage(p ? Ab0 : Ab1, p ? Bb0 : Bb1, kt + 1);
    __builtin_amdgcn_s_setprio(1);
#pragma unroll
    for (int mt = 0; mt < 4; ++mt)
#pragma unroll
      for (int nt = 0; nt < 4; ++nt)
        acc[mt][nt] = __builtin_amdgcn_mfma_f32_16x16x32_bf16(
            af[mt], bfr[nt], acc[mt][nt], 0, 0, 0);
    __builtin_amdgcn_s_setprio(0);
    // c = 1 fragments
#pragma unroll
    for (int t = 0; t < 4; ++t) {
      const int ra = wr * 64 + t * 16 + lr;
      const int rb = wc * 64 + t * 16 + lr;
      af[t] = *(const bf16x8*)(Ard + ra * 128 + ((64 + lg * 16) ^ ((ra & 7) << 4)));
      bfr[t] = *(const bf16x8*)(Brd + rb * 128 + ((64 + lg * 16) ^ ((rb & 7) << 4)));
    }
    __builtin_amdgcn_s_setprio(1);
#pragma unroll
    for (int mt = 0; mt < 4; ++mt)
#pragma unroll
      for (int nt = 0; nt < 4; ++nt)
        acc[mt][nt] = __builtin_amdgcn_mfma_f32_16x16x32_bf16(
            af[mt], bfr[nt], acc[mt][nt], 0, 0, 0);
    __builtin_amdgcn_s_setprio(0);
    __syncthreads();
  }

  if (MODE == 1) {
#pragma unroll
    for (int mt = 0; mt < 4; ++mt) {
      const int row0 = bm + wr * 64 + mt * 16 + lg * 4;
#pragma unroll
      for (int nt = 0; nt < 4; ++nt) {
        const int col = bn + wc * 64 + nt * 16 + lr;
        const float bv = bias[col];
#pragma unroll
        for (int r = 0; r < 4; ++r)
          outF[(size_t)(row0 + r) * N + col] = acc[mt][nt][r] + bv;
      }
    }
    return;
  }

  // ---- MODE 0: bounce acc -> swizzled LDS tile T (256 B rows), then ----
  // ---- coalesced fragment-packed global stores (1 KiB per wave). ----
  u16* T = smem;  // 32 KiB, buffers dead after last barrier
  const int which = bn >> 10;  // 0=Q, 1=K, 2=V (block is entirely one of them)

  if (which == 2) {
    // V: store transposed T[d_col][token] so frag chunks are row-contiguous
#pragma unroll
    for (int nt = 0; nt < 4; ++nt) {
      const int cl = wc * 64 + nt * 16 + lr;  // d col (T row)
      const float bv = bias[bn + cl];
#pragma unroll
      for (int mt = 0; mt < 4; ++mt) {
        const int rlb = wr * 128 + mt * 32 + lg * 8;  // token byte base
        ushort4v pk;
#pragma unroll
        for (int r = 0; r < 4; ++r) pk[r] = f2bf(acc[mt][nt][r] + bv);
        *(ushort4v*)((char*)T + cl * 256 + (rlb ^ ((cl & 7) << 4))) = pk;
      }
    }
  } else {
    const float sc = (which == 0) ? 0.125f : 1.0f;
#pragma unroll
    for (int mt = 0; mt < 4; ++mt) {
      const int rl0 = wr * 64 + mt * 16 + lg * 4;
#pragma unroll
      for (int nt = 0; nt < 4; ++nt) {
        const int cl = wc * 64 + nt * 16 + lr;
        const float bv = bias[bn + cl];
#pragma unroll
        for (int r = 0; r < 4; ++r) {
          const int rl = rl0 + r;
          *(u16*)((char*)T + rl * 256 + ((cl * 2) ^ ((rl & 7) << 4))) =
              f2bf((acc[mt][nt][r] + bv) * sc);
        }
      }
    }
  }
  __syncthreads();

  const int b = bm >> 11;
  const int nbase = bm & 2047;
  if (which == 0) {
#pragma unroll
    for (int i = 0; i < 8; ++i) {
      const int c = i * 256 + tid;
      const int rl = c >> 4, dch = c & 15;
      uint4v v =
          *(const uint4v*)((const char*)T + rl * 256 + ((dch * 16) ^ ((rl & 7) << 4)));
      const int bh = b * 16 + (bn >> 6) + (dch >> 3);
      *(uint4v*)(Qb + ((size_t)bh * 2048 + nbase + rl) * 64 + (dch & 7) * 8) = v;
    }
  } else if (which == 1) {
    // K frags: s=2t+rtile holds K[kt2*64+rtile*32+lq][16t+8hi+j] at lane hi*32+lq
#pragma unroll
    for (int i = 0; i < 8; ++i) {
      const int c = i * 256 + tid;
      const int lane = c & 63, s = (c >> 6) & 7, ktl = (c >> 9) & 1, hl = c >> 10;
      const int lq = lane & 31, hi2 = lane >> 5;
      const int rl = ktl * 64 + (s & 1) * 32 + lq;
      const int cc = hl * 128 + (s >> 1) * 32 + hi2 * 16;
      uint4v v = *(const uint4v*)((const char*)T + rl * 256 + (cc ^ ((rl & 7) << 4)));
      const int bh = b * 16 + ((bn & 1023) >> 6) + hl;
      const int kt2 = (nbase >> 6) + ktl;
      *(uint4v*)(Kb + ((((size_t)bh * 32 + kt2) * 8 + s) * 64 + lane) * 8) = v;
    }
  } else {
    // V frags: s=2t+dtile holds V[kt2*64+16t+8hi+j][dtile*32+lq] at lane hi*32+lq
#pragma unroll
    for (int i = 0; i < 8; ++i) {
      const int c = i * 256 + tid;
      const int lane = c & 63, s = (c >> 6) & 7, ktl = (c >> 9) & 1, hl = c >> 10;
      const int lq = lane & 31, hi2 = lane >> 5;
      const int cl = hl * 64 + (s & 1) * 32 + lq;
      const int cc = ktl * 128 + (s >> 1) * 32 + hi2 * 16;
      uint4v v = *(const uint4v*)((const char*)T + cl * 256 + (cc ^ ((cl & 7) << 4)));
      const int bh = b * 16 + ((bn & 1023) >> 6) + hl;
      const int kt2 = (nbase >> 6) + ktl;
      *(uint4v*)(Vb + ((((size_t)bh * 32 + kt2) * 8 + s) * 64 + lane) * 8) = v;
    }
  }
}

// ---------------- flash attention v3: barrier-free, LDS-free, reg-resident ----
__global__ __launch_bounds__(512, 2) void flash_attn3(const u16* __restrict__ Qb,
                                                      const u16* __restrict__ Kp,
                                                      const u16* __restrict__ Vp,
                                                      u16* __restrict__ AO) {
  const int bh = blockIdx.x & 31;
  const int qt = blockIdx.x >> 5;
  const int tid = threadIdx.x;
  const int w = tid >> 6;
  const int lane = tid & 63;
  const int lq = lane & 31;
  const int hi = lane >> 5;
  const int q0 = qt * 256 + w * 32;

  const u16* Qg = Qb + ((size_t)bh * 2048 + q0 + lq) * 64 + 8 * hi;
  bf16x8 qf[4];
#pragma unroll
  for (int t = 0; t < 4; ++t) qf[t] = *(const bf16x8*)(Qg + 16 * t);

  const u16* Kg = Kp + (size_t)bh * (32 * 4096) + lane * 8;
  const u16* Vg = Vp + (size_t)bh * (32 * 4096) + lane * 8;

  f32x16 ot0 = {}, ot1 = {};
  float m = -1e30f, lsum = 0.f;
  const float LOG2E = 1.44269504f;

  bf16x8 kbuf[8], vbuf[8];
#pragma unroll
  for (int s = 0; s < 8; ++s) kbuf[s] = *(const bf16x8*)(Kg + s * 512);

  for (int kt = 0; kt < 32; ++kt) {
#pragma unroll
    for (int s = 0; s < 8; ++s)
      vbuf[s] = *(const bf16x8*)(Vg + (size_t)kt * 4096 + s * 512);

    f32x16 sa = {}, sb = {};
    __builtin_amdgcn_s_setprio(1);
#pragma unroll
    for (int t = 0; t < 4; ++t) {
      sa = __builtin_amdgcn_mfma_f32_32x32x16_bf16(kbuf[2 * t], qf[t], sa, 0, 0, 0);
      sb = __builtin_amdgcn_mfma_f32_32x32x16_bf16(kbuf[2 * t + 1], qf[t], sb, 0, 0, 0);
    }
    __builtin_amdgcn_s_setprio(0);

    if (kt < 31) {
#pragma unroll
      for (int s = 0; s < 8; ++s)
        kbuf[s] = *(const bf16x8*)(Kg + (size_t)(kt + 1) * 4096 + s * 512);
    }

    float tmax[8];
#pragma unroll
    for (int r = 0; r < 8; ++r)
      tmax[r] = fmaxf(fmaxf(sa[r], sa[r + 8]), fmaxf(sb[r], sb[r + 8]));
#pragma unroll
    for (int st = 4; st > 0; st >>= 1)
#pragma unroll
      for (int r = 0; r < st; ++r) tmax[r] = fmaxf(tmax[r], tmax[r + st]);
    float pmax = fmaxf(tmax[0], __shfl_xor(tmax[0], 32, 64));

    if (__any(pmax > m + 8.0f)) {
      const float newm = fmaxf(m, pmax);
      const float corr = exp2f((m - newm) * LOG2E);
      m = newm;
      lsum *= corr;
#pragma unroll
      for (int r = 0; r < 16; ++r) { ot0[r] *= corr; ot1[r] *= corr; }
    }

    const float mk = m * LOG2E;
#pragma unroll
    for (int r = 0; r < 16; ++r) {
      sa[r] = exp2f(fmaf(sa[r], LOG2E, -mk));
      sb[r] = exp2f(fmaf(sb[r], LOG2E, -mk));
    }

    float tsum[8];
#pragma unroll
    for (int r = 0; r < 8; ++r)
      tsum[r] = (sa[r] + sa[r + 8]) + (sb[r] + sb[r + 8]);
#pragma unroll
    for (int st = 4; st > 0; st >>= 1)
#pragma unroll
      for (int r = 0; r < st; ++r) tsum[r] += tsum[r + st];
    lsum += tsum[0] + __shfl_xor(tsum[0], 32, 64);

    unsigned Ua[8], Ub[8];
#pragma unroll
    for (int s = 0; s < 4; ++s)
#pragma unroll
      for (int m2 = 0; m2 < 2; ++m2) {
        Ua[s * 2 + m2] = cvt_pk_bf16(sa[4 * s + 2 * m2], sa[4 * s + 2 * m2 + 1]);
        Ub[s * 2 + m2] = cvt_pk_bf16(sb[4 * s + 2 * m2], sb[4 * s + 2 * m2 + 1]);
      }
    bf16x8 pfrag[4];
#pragma unroll
    for (int t = 0; t < 4; ++t) {
      const unsigned* U = (t < 2) ? Ua : Ub;
      const int tt = t & 1;
      unsigned w0 = U[(2 * tt) * 2 + 0], w2 = U[(2 * tt + 1) * 2 + 0];
      unsigned w1 = U[(2 * tt) * 2 + 1], w3 = U[(2 * tt + 1) * 2 + 1];
      perm32swap(w0, w2);
      perm32swap(w1, w3);
      uint4v uu = {w0, w1, w2, w3};
      pfrag[t] = __builtin_bit_cast(bf16x8, uu);
    }

    __builtin_amdgcn_s_setprio(1);
#pragma unroll
    for (int t = 0; t < 4; ++t) {
      ot0 = __builtin_amdgcn_mfma_f32_32x32x16_bf16(vbuf[2 * t], pfrag[t], ot0, 0, 0, 0);
      ot1 = __builtin_amdgcn_mfma_f32_32x32x16_bf16(vbuf[2 * t + 1], pfrag[t], ot1, 0, 0, 0);
    }
    __builtin_amdgcn_s_setprio(0);
  }

  const float inv = 1.0f / lsum;
  const int b = bh >> 4, h = bh & 15;
  u16* Ao = AO + ((size_t)(b * 2048 + q0 + lq)) * 1024 + h * 64;
#pragma unroll
  for (int s = 0; s < 4; ++s) {
    {
      const int d = 8 * s + 4 * hi;
      ushort4v pk;
#pragma unroll
      for (int i = 0; i < 4; ++i) pk[i] = f2bf(ot0[4 * s + i] * inv);
      *(ushort4v*)(Ao + d) = pk;
    }
    {
      const int d = 32 + 8 * s + 4 * hi;
      ushort4v pk;
#pragma unroll
      for (int i = 0; i < 4; ++i) pk[i] = f2bf(ot1[4 * s + i] * inv);
      *(ushort4v*)(Ao + d) = pk;
    }
  }
}

// ---------------- launch ----------------
extern "C" void kernel_launch(void* const* d_in, const int* in_sizes, int n_in,
                              void* d_out, int out_size, void* d_ws, size_t ws_size,
                              hipStream_t stream) {
  const float* x = (const float*)d_in[0];
  const float* w_qkv = (const float*)d_in[1];
  const float* b_qkv = (const float*)d_in[2];
  const float* w_proj = (const float*)d_in[3];
  const float* b_proj = (const float*)d_in[4];
  float* out = (float*)d_out;

  char* ws = (char*)d_ws;
  u16* xb = (u16*)(ws);                          // 8 MiB  [4096][1024]
  u16* wqT = (u16*)(ws + (8ull << 20));          // 6 MiB  [3072][1024]
  u16* wpT = (u16*)(ws + (14ull << 20));         // 2 MiB  [1024][1024]
  u16* Qb = (u16*)(ws + (16ull << 20));          // 8 MiB  [32][2048][64]
  u16* Kp = (u16*)(ws + (24ull << 20));          // 8 MiB  packed frags
  u16* Vp = (u16*)(ws + (32ull << 20));          // 8 MiB  packed frags
  u16* AO = (u16*)(ws + (40ull << 20));          // 8 MiB  [4096][1024]

  cvt_bf16<<<dim3(2048), dim3(256), 0, stream>>>(x, xb, 4194304);
  trans_w<<<dim3(16, 48), dim3(256), 0, stream>>>(w_qkv, wqT, 1024, 3072);
  trans_w<<<dim3(16, 16), dim3(256), 0, stream>>>(w_proj, wpT, 1024, 1024);
  gemm_bt<0><<<dim3(32, 24), dim3(256), 0, stream>>>(xb, wqT, 4096, 3072, 1024,
                                                     b_qkv, nullptr, Qb, Kp, Vp);
  flash_attn3<<<dim3(256), dim3(512), 0, stream>>>(Qb, Kp, Vp, AO);
  gemm_bt<1><<<dim3(32, 8), dim3(256), 0, stream>>>(AO, wpT, 4096, 1024, 1024,
                                                    b_proj, out, nullptr, nullptr,
                                                    nullptr);
}